// Round 1
// baseline (157.680 us; speedup 1.0000x reference)
//
#include <hip/hip_runtime.h>

typedef _Float16 f16;
typedef _Float16 f16x4 __attribute__((ext_vector_type(4)));
typedef _Float16 f16x8 __attribute__((ext_vector_type(8)));
typedef float    f32x4 __attribute__((ext_vector_type(4)));

#define Kn   10
#define En   90
#define BM   128
#define WE_ELEMS (90*128*128)   // f16 elems of transposed W_edge

__device__ __forceinline__ float fast_exp2(float x){
#if __has_builtin(__builtin_amdgcn_exp2f)
    return __builtin_amdgcn_exp2f(x);
#else
    return exp2f(x);
#endif
}
__device__ __forceinline__ float fast_rcp(float x){
#if __has_builtin(__builtin_amdgcn_rcpf)
    return __builtin_amdgcn_rcpf(x);
#else
    return 1.0f/x;
#endif
}
// tanh(x) = 1 - 2/(e^{2x}+1); e^{2x}=2^{x*2*log2(e)}. Safe at +-inf ends.
__device__ __forceinline__ float tanh_fast(float x){
    float e = fast_exp2(x * 2.88539008177792681472f);
    return 1.0f - 2.0f * fast_rcp(e + 1.0f);
}

// W_edge [E][128f][128h] f32  ->  [E][128h][128f] f16 (k-contiguous B-operand)
__global__ void we_transpose(const float* __restrict__ We, f16* __restrict__ out){
    int gid = blockIdx.x*256 + threadIdx.x;   // 90*2048 = 184320 threads
    int e  = gid >> 11;
    int r  = gid & 2047;
    int h  = r & 127;
    int f0 = (r >> 7) << 3;
    const float* src = We + e*16384 + h;
    f16x8 v;
    #pragma unroll
    for (int k=0;k<8;k++) v[k] = (f16)src[(f0+k)*128];
    *(f16x8*)(out + e*16384 + h*128 + f0) = v;
}

// W_node [K][208f][64d] f32 -> [K][64d][224f] f16, zero-padded f 208..223
__global__ void wn_transpose(const float* __restrict__ Wn, f16* __restrict__ out){
    int gid = blockIdx.x*256 + threadIdx.x;   // 10*64*224 = 143360
    int k = gid / 14336;
    int r = gid - k*14336;
    int d = r / 224;
    int f = r - d*224;
    float v = (f < 208) ? Wn[k*13312 + f*64 + d] : 0.0f;
    out[gid] = (f16)v;
}

__launch_bounds__(256, 2)
__global__ void gnn_main(const float* __restrict__ states,
                         const float* __restrict__ action,
                         const float* __restrict__ b_edge,
                         const float* __restrict__ b_node,
                         const f16*  __restrict__ We_t,
                         const f16*  __restrict__ Wn_t,
                         float* __restrict__ out)
{
    // sAi [128][72] f16, sAj [128][72] f16 (also holds action cols 0..15 in stage2),
    // union region: sW [128][136] (stage1 W) / sAgg [128][152] (stage2, cols 128..143 zero)
    __shared__ alignas(16) f16 S[9216 + 9216 + 19456];   // 75776 B -> 2 blocks/CU
    f16* sAi = S;
    f16* sAj = S + 9216;
    f16* sWU = S + 18432;

    const int t    = threadIdx.x;
    const int b0   = blockIdx.x * BM;
    const int i    = blockIdx.y;
    const int lane = t & 63;
    const int wid  = t >> 6;
    const int l15  = lane & 15;
    const int q    = lane >> 4;
    const int qo   = q << 3;
    // stage-1 wave tile: 64x64; wave grid 2x2
    const int wr = (wid >> 1) * 64;
    const int wc = (wid & 1) * 64;

    // ---- stage states_i (fp32 -> f16) ----
    #pragma unroll
    for (int it=0; it<8; ++it){
        int cid = it*256 + t;              // 2048 chunks x 4 floats
        int row = cid >> 4;
        int c4  = (cid & 15) << 2;
        const float4 v = *(const float4*)(states + (b0+row)*640 + i*64 + c4);
        f16x4 hv; hv[0]=(f16)v.x; hv[1]=(f16)v.y; hv[2]=(f16)v.z; hv[3]=(f16)v.w;
        *(f16x4*)(sAi + row*72 + c4) = hv;
    }

    f32x4 agg[4][4] = {};

    #pragma unroll 1
    for (int et=0; et<9; ++et){
        const int j = et + (et >= i);      // DST node for edge (i,j), lexicographic
        const int e = 9*i + et;

        // stage states_j
        #pragma unroll
        for (int it=0; it<8; ++it){
            int cid = it*256 + t;
            int row = cid >> 4;
            int c4  = (cid & 15) << 2;
            const float4 v = *(const float4*)(states + (b0+row)*640 + j*64 + c4);
            f16x4 hv; hv[0]=(f16)v.x; hv[1]=(f16)v.y; hv[2]=(f16)v.z; hv[3]=(f16)v.w;
            *(f16x4*)(sAj + row*72 + c4) = hv;
        }
        // stage W_edge[e] (already f16, transposed [h][f])
        const f16* wsrc = We_t + e*16384;
        #pragma unroll
        for (int it=0; it<8; ++it){
            int cid = it*256 + t;          // 2048 chunks x 8 f16
            int h   = cid >> 4;
            int c8  = (cid & 15) << 3;
            *(f16x8*)(sWU + h*136 + c8) = *(const f16x8*)(wsrc + h*128 + c8);
        }
        __syncthreads();

        f32x4 msg[4][4] = {};
        #pragma unroll
        for (int ks=0; ks<4; ++ks){
            const f16* ab = (ks<2) ? (sAi + ks*32) : (sAj + (ks-2)*32);
            f16x8 af[4], bf[4];
            #pragma unroll
            for (int rt=0; rt<4; ++rt)
                af[rt] = *(const f16x8*)(ab + (wr + rt*16 + l15)*72 + qo);
            #pragma unroll
            for (int c=0; c<4; ++c)
                bf[c] = *(const f16x8*)(sWU + (wc + c*16 + l15)*136 + ks*32 + qo);
            #pragma unroll
            for (int rt=0; rt<4; ++rt)
                #pragma unroll
                for (int c=0; c<4; ++c)
                    msg[rt][c] = __builtin_amdgcn_mfma_f32_16x16x32_f16(af[rt], bf[c], msg[rt][c], 0,0,0);
        }
        // bias + tanh + aggregate (segment-sum over the 9 edges sourced at i)
        float bias[4];
        #pragma unroll
        for (int c=0;c<4;c++) bias[c] = b_edge[e*128 + wc + c*16 + l15];
        #pragma unroll
        for (int rt=0; rt<4; ++rt)
            #pragma unroll
            for (int c=0;c<4;c++)
                #pragma unroll
                for (int r2=0;r2<4;r2++)
                    agg[rt][c][r2] += tanh_fast(msg[rt][c][r2] + bias[c]);
        __syncthreads();   // protect sAj/sW before next edge's staging
    }

    // ---- agg (C-layout regs) -> LDS f16 A-layout; zero pad; stage action ----
    #pragma unroll
    for (int rt=0; rt<4; ++rt)
        #pragma unroll
        for (int c=0;c<4;c++)
            #pragma unroll
            for (int r2=0;r2<4;r2++){
                int row = wr + rt*16 + q*4 + r2;
                int col = wc + c*16 + l15;
                sWU[row*152 + col] = (f16)agg[rt][c][r2];
            }
    {   // zero cols 128..143 (K-pad of stage-2)
        int row = t >> 1, c0 = 128 + ((t & 1) << 3);
        f16x8 z; 
        #pragma unroll
        for (int k=0;k<8;k++) z[k] = (f16)0.0f;
        *(f16x8*)(sWU + row*152 + c0) = z;
    }
    #pragma unroll
    for (int it=0; it<2; ++it){            // action [128][16] -> sAj cols 0..15
        int cid = it*256 + t;
        int row = cid >> 2;
        int c4  = (cid & 3) << 2;
        const float4 v = *(const float4*)(action + (b0+row)*160 + i*16 + c4);
        f16x4 hv; hv[0]=(f16)v.x; hv[1]=(f16)v.y; hv[2]=(f16)v.z; hv[3]=(f16)v.w;
        *(f16x4*)(sAj + row*72 + c4) = hv;
    }
    __syncthreads();

    // ---- stage 2: out = tanh([states|action|agg] @ W_node[i] + b_node[i]) ----
    // wave tile 32x64: rows wid*32..+32, all 64 cols; K = 224 (7 steps)
    f32x4 acc[2][4] = {};
    const f16* wn = Wn_t + i*14336;
    #pragma unroll
    for (int ks=0; ks<7; ++ks){
        int kk = ks*32 + qo;
        f16x8 af[2], bf[4];
        #pragma unroll
        for (int rt=0; rt<2; ++rt){
            int row = wid*32 + rt*16 + l15;
            const f16* ap = (kk < 64) ? (sAi + row*72 + kk)
                          : (kk < 80) ? (sAj + row*72 + (kk-64))
                                      : (sWU + row*152 + (kk-80));
            af[rt] = *(const f16x8*)ap;
        }
        #pragma unroll
        for (int c=0;c<4;c++)
            bf[c] = *(const f16x8*)(wn + (c*16 + l15)*224 + kk);
        #pragma unroll
        for (int rt=0; rt<2; ++rt)
            #pragma unroll
            for (int c=0;c<4;c++)
                acc[rt][c] = __builtin_amdgcn_mfma_f32_16x16x32_f16(af[rt], bf[c], acc[rt][c], 0,0,0);
    }
    float bn[4];
    #pragma unroll
    for (int c=0;c<4;c++) bn[c] = b_node[i*64 + c*16 + l15];
    #pragma unroll
    for (int rt=0; rt<2; ++rt)
        #pragma unroll
        for (int c=0;c<4;c++)
            #pragma unroll
            for (int r2=0;r2<4;r2++){
                int row = wid*32 + rt*16 + q*4 + r2;
                int col = c*16 + l15;
                out[((b0+row)*10 + i)*64 + col] = tanh_fast(acc[rt][c][r2] + bn[c]);
            }
}

extern "C" void kernel_launch(void* const* d_in, const int* in_sizes, int n_in,
                              void* d_out, int out_size, void* d_ws, size_t ws_size,
                              hipStream_t stream) {
    const float* states = (const float*)d_in[0];
    const float* action = (const float*)d_in[1];
    const float* W_edge = (const float*)d_in[2];
    const float* b_edge = (const float*)d_in[3];
    const float* W_node = (const float*)d_in[4];
    const float* b_node = (const float*)d_in[5];
    f16* We_t = (f16*)d_ws;                 // 2,949,120 B
    f16* Wn_t = We_t + WE_ELEMS;            // +286,720 B  (total ws use ~3.24 MB)

    hipLaunchKernelGGL(we_transpose, dim3(720), dim3(256), 0, stream, W_edge, We_t);
    hipLaunchKernelGGL(wn_transpose, dim3(560), dim3(256), 0, stream, W_node, Wn_t);
    hipLaunchKernelGGL(gnn_main, dim3(8192/BM, Kn), dim3(256), 0, stream,
                       states, action, b_edge, b_node, We_t, Wn_t, (float*)d_out);
}